// Round 10
// baseline (47.614 us; speedup 1.0000x reference)
//
#include <hip/hip_runtime.h>
#include <math.h>

#define NN 50000
#define NE 800000
#define KD 256      // 2*D
#define DD 128
#define ROWS 16     // rows per wave-tile (50000 = 3125 * 16, exact)
#define NTILE 3125

// SpMV privatization geometry
#define EC 64
#define NR 4
#define RNG 12500
#define QPC 3125

// workspace layout (floats)
#define S_OFF   0
#define P_OFF   50176
#define CNT_OFF (P_OFF + EC * NN)
#define W1P_OFF (CNT_OFF + 16)
#define WS_NEED ((size_t)(W1P_OFF + DD * KD / 2 + 16) * 4)

typedef __bf16 bf16x4 __attribute__((ext_vector_type(4)));
typedef __bf16 bf16x8 __attribute__((ext_vector_type(8)));
typedef float f32x4 __attribute__((ext_vector_type(4)));

// Prep: W1 f32 [128][256] -> FRAGMENT-MAJOR bf16; also zero out/counter.
// W1p[((dt*8+ks)*64 + g*16+li)*8 + j] = W1[(dt*16+li)*256 + ks*32 + g*8 + j]
__global__ void prep_w1_kernel(const float* __restrict__ W1, __bf16* __restrict__ W1p,
                               float* __restrict__ out, unsigned* __restrict__ counter)
{
    int i = blockIdx.x * 256 + threadIdx.x;   // one per (d, ks, g): 128*8*4 = 4096
    if (i == 0) { out[0] = 0.f; counter[0] = 0u; }
    if (i >= DD * 8 * 4) return;
    int g  = i & 3;
    int ks = (i >> 2) & 7;
    int d  = i >> 5;
    int dt = d >> 4, li = d & 15;
    const float* src = W1 + d * KD + ks * 32 + g * 8;
    float4 v0 = *(const float4*)(src);
    float4 v1 = *(const float4*)(src + 4);
    bf16x8 h = { (__bf16)v0.x, (__bf16)v0.y, (__bf16)v0.z, (__bf16)v0.w,
                 (__bf16)v1.x, (__bf16)v1.y, (__bf16)v1.z, (__bf16)v1.w };
    *(bf16x8*)&W1p[(size_t)(((dt * 8 + ks) * 64) + g * 16 + li) * 8] = h;
}

// Stage 1 (barrier-free, LDS-free): one wave = one 16-row tile x all 128 d.
// A loaded per-lane directly from global (lane (g,li): row li, cols ks*128B+g*32B --
// 64 lanes tile 16 rows x 128 B contiguous per instruction pair, full-line coalesced,
// no cross-wave redundancy). B streamed from frag-major W1p (64 KB, L1/L2-hot).
// k = ks*32 + g*8 + j on BOTH sides (same bijection -> HW k-order independent).
__global__ __launch_bounds__(256, 4) void stage1_kernel(
    const float* __restrict__ x, const __bf16* __restrict__ W1p,
    const float* __restrict__ b1, const float* __restrict__ W2,
    float* __restrict__ s)
{
    const int tid  = threadIdx.x;
    const int lane = tid & 63;
    const int w    = tid >> 6;
    const int g    = lane >> 4;
    const int li   = lane & 15;
    const int tw   = blockIdx.x * 4 + w;     // wave-tile id
    if (tw >= NTILE) return;                 // no barriers -> divergent exit safe
    const int m0   = tw * ROWS;

    // Per-lane A row base: lane (g,li) reads row (m0+li), k-window g*8
    const float* xrow = x + (size_t)(m0 + li) * KD + g * 8;

    // b1 / W2 for this lane's d-column in each of the 8 d-tiles
    float b1v[8], w2v[8];
    #pragma unroll
    for (int dt = 0; dt < 8; ++dt) { b1v[dt] = b1[dt * 16 + li]; w2v[dt] = W2[dt * 16 + li]; }

    const __bf16* fbase = W1p + (size_t)lane * 8;

    f32x4 acc[8] = {};   // one accumulator per d-tile; 8 independent MFMA chains
    #pragma unroll
    for (int ks = 0; ks < 8; ++ks) {
        float4 al = *(const float4*)(xrow + ks * 32);
        float4 ah = *(const float4*)(xrow + ks * 32 + 4);
        bf16x8 a = { (__bf16)al.x, (__bf16)al.y, (__bf16)al.z, (__bf16)al.w,
                     (__bf16)ah.x, (__bf16)ah.y, (__bf16)ah.z, (__bf16)ah.w };
        #pragma unroll
        for (int dt = 0; dt < 8; ++dt) {
            bf16x8 bfr = *(const bf16x8*)(fbase + (size_t)((dt * 8 + ks) * 64) * 8);
            acc[dt] = __builtin_amdgcn_mfma_f32_16x16x32_bf16(a, bfr, acc[dt], 0, 0, 0);
        }
    }

    // Epilogue: v = sum_dt sin(acc+b1)*W2, reduce over the 16 d-lanes (li), store s.
    // C/D layout: col(d)=li, row(m)=g*4+r  =>  m = m0 + g*4 + r.
    #pragma unroll
    for (int r = 0; r < 4; ++r) {
        float v = 0.f;
        #pragma unroll
        for (int dt = 0; dt < 8; ++dt)
            v += __sinf(acc[dt][r] + b1v[dt]) * w2v[dt];
        v += __shfl_xor(v, 1); v += __shfl_xor(v, 2);
        v += __shfl_xor(v, 4); v += __shfl_xor(v, 8);
        if (li == 0) s[m0 + g * 4 + r] = v;
    }
}

// Stage 2 (LDS-privatized): block (nr, ecid) scans chunk ecid, accumulates its node
// range in LDS, writes partial range to P[ecid][...]. No device-scope atomics.
__global__ __launch_bounds__(1024, 1) void spmv_lds_kernel(
    const int* __restrict__ erow, const int* __restrict__ ecol,
    const float* __restrict__ ew, const float* __restrict__ s,
    float* __restrict__ P)
{
    __shared__ float lt[RNG];
    const int tid  = threadIdx.x;
    const int ecid = blockIdx.x & 63;
    const int nr   = blockIdx.x >> 6;
    const int base = nr * RNG;

    for (int i = tid; i < RNG; i += 1024) lt[i] = 0.f;
    __syncthreads();

    const int4*   r4p = (const int4*)erow;
    const int4*   c4p = (const int4*)ecol;
    const float4* w4p = (const float4*)ew;
    for (int q = tid; q < QPC; q += 1024) {
        int i = ecid * QPC + q;
        int4   r4 = r4p[i];
        int4   c4 = c4p[i];
        float4 w4 = w4p[i];
        unsigned a;
        a = (unsigned)(r4.x - base); if (a < RNG) atomicAdd(&lt[a], w4.x * s[c4.x]);
        a = (unsigned)(r4.y - base); if (a < RNG) atomicAdd(&lt[a], w4.y * s[c4.y]);
        a = (unsigned)(r4.z - base); if (a < RNG) atomicAdd(&lt[a], w4.z * s[c4.z]);
        a = (unsigned)(r4.w - base); if (a < RNG) atomicAdd(&lt[a], w4.w * s[c4.w]);
    }
    __syncthreads();

    float4*       dst = (float4*)(P + (size_t)ecid * NN + base);
    const float4* src = (const float4*)lt;
    for (int j = tid; j < RNG / 4; j += 1024) dst[j] = src[j];
}

// Stage 3: out += sum_n sin(sum_ec P[ec][n] + b2)^2 ; last block applies sqrt.
__global__ void finish_lds_kernel(const float* __restrict__ P, const float* __restrict__ b2,
                                  float* __restrict__ out, unsigned* __restrict__ counter,
                                  int nblocks)
{
    int n = blockIdx.x * 256 + threadIdx.x;
    float v = 0.f;
    if (n < NN) {
        float a = 0.f;
        #pragma unroll 8
        for (int ec = 0; ec < EC; ++ec) a += P[(size_t)ec * NN + n];
        float o = __sinf(a + b2[0]);
        v = o * o;
    }
    #pragma unroll
    for (int off = 32; off; off >>= 1) v += __shfl_xor(v, off);
    __shared__ float partial[4];
    if ((threadIdx.x & 63) == 0) partial[threadIdx.x >> 6] = v;
    __syncthreads();
    if (threadIdx.x == 0) {
        atomicAdd(out, partial[0] + partial[1] + partial[2] + partial[3]);
        __threadfence();
        unsigned old = atomicAdd(counter, 1u);
        if (old == (unsigned)(nblocks - 1)) {
            float tot = atomicAdd(out, 0.f);   // atomic read: all prior adds visible
            out[0] = sqrtf(tot);
        }
    }
}

// ---- Fallback path (small workspace): dense atomic SpMV ----
__global__ void spmv_fallback_kernel(const int* __restrict__ erow, const int* __restrict__ ecol,
                                     const float* __restrict__ ew, const float* __restrict__ s,
                                     float* __restrict__ t)
{
    int i = blockIdx.x * 256 + threadIdx.x;
    if (i >= NE / 4) return;
    int4   r4 = ((const int4*)erow)[i];
    int4   c4 = ((const int4*)ecol)[i];
    float4 w4 = ((const float4*)ew)[i];
    atomicAdd(&t[r4.x], w4.x * s[c4.x]);
    atomicAdd(&t[r4.y], w4.y * s[c4.y]);
    atomicAdd(&t[r4.z], w4.z * s[c4.z]);
    atomicAdd(&t[r4.w], w4.w * s[c4.w]);
}

__global__ void finish_fallback_kernel(const float* __restrict__ t, const float* __restrict__ b2,
                                       float* __restrict__ out)
{
    int n = blockIdx.x * 256 + threadIdx.x;
    float v = 0.f;
    if (n < NN) { float o = __sinf(t[n] + b2[0]); v = o * o; }
    #pragma unroll
    for (int off = 32; off; off >>= 1) v += __shfl_xor(v, off);
    __shared__ float partial[4];
    if ((threadIdx.x & 63) == 0) partial[threadIdx.x >> 6] = v;
    __syncthreads();
    if (threadIdx.x == 0)
        atomicAdd(out, partial[0] + partial[1] + partial[2] + partial[3]);
}

__global__ void sqrt_kernel(float* out) { out[0] = sqrtf(out[0]); }

__global__ void zero_kernel(float* t, float* out)
{
    int i = blockIdx.x * 256 + threadIdx.x;
    if (i < NN) t[i] = 0.f;
    if (i == 0) out[0] = 0.f;
}

extern "C" void kernel_launch(void* const* d_in, const int* in_sizes, int n_in,
                              void* d_out, int out_size, void* d_ws, size_t ws_size,
                              hipStream_t stream)
{
    const float* x   = (const float*)d_in[0];
    const float* W1  = (const float*)d_in[1];
    const float* b1  = (const float*)d_in[2];
    const float* W2  = (const float*)d_in[3];
    const float* b2  = (const float*)d_in[4];
    const int*   er  = (const int*)d_in[5];
    const int*   ec  = ((const int*)d_in[5]) + NE;
    const float* ew  = (const float*)d_in[6];
    float* out = (float*)d_out;

    float*    ws    = (float*)d_ws;
    float*    s_buf = ws + S_OFF;
    float*    P     = ws + P_OFF;
    unsigned* cnt   = (unsigned*)(ws + CNT_OFF);
    __bf16*   W1p   = (__bf16*)(ws + W1P_OFF);

    const int s1_grid = (NTILE + 3) / 4;   // 782 blocks x 4 wave-tiles

    if (ws_size >= WS_NEED) {
        prep_w1_kernel<<<16, 256, 0, stream>>>(W1, W1p, out, cnt);
        stage1_kernel<<<s1_grid, 256, 0, stream>>>(x, W1p, b1, W2, s_buf);
        spmv_lds_kernel<<<NR * EC, 1024, 0, stream>>>(er, ec, ew, s_buf, P);
        int fb = (NN + 255) / 256;
        finish_lds_kernel<<<fb, 256, 0, stream>>>(P, b2, out, cnt, fb);
    } else {
        // Dense-atomic fallback (needs ~700 KB of ws)
        float*    t    = ws + P_OFF;
        __bf16*   W1pf = (__bf16*)(ws + P_OFF + NN);
        unsigned* cntf = (unsigned*)(ws + P_OFF + NN + DD * KD / 2);
        prep_w1_kernel<<<16, 256, 0, stream>>>(W1, W1pf, out, cntf);
        zero_kernel<<<(NN + 255) / 256, 256, 0, stream>>>(t, out);
        stage1_kernel<<<s1_grid, 256, 0, stream>>>(x, W1pf, b1, W2, s_buf);
        spmv_fallback_kernel<<<(NE / 4 + 255) / 256, 256, 0, stream>>>(er, ec, ew, s_buf, t);
        finish_fallback_kernel<<<(NN + 255) / 256, 256, 0, stream>>>(t, b2, out);
        sqrt_kernel<<<1, 1, 0, stream>>>(out);
    }
}